// Round 14
// baseline (1433.997 us; speedup 1.0000x reference)
//
#include <hip/hip_runtime.h>

#define NB    128
#define P     512
#define PP    262144            // P*P
#define TOT   33554432          // NB*PP
#define MAX_IT 100

// d_ws layout (float offsets)
#define WS_W   0                // 262144 : |1/(s.s^T)+1e-5|
#define WS_K   262144           // bf16[TOT] = 16777216 float slots

typedef float f32x2 __attribute__((ext_vector_type(2)));
typedef float f32x4 __attribute__((ext_vector_type(4)));

__device__ __forceinline__ f32x2 pkfma(f32x2 a, f32x2 b, f32x2 c) {
  f32x2 d;
  asm("v_pk_fma_f32 %0, %1, %2, %3" : "=v"(d) : "v"(a), "v"(b), "v"(c));
  return d;
}

__device__ __forceinline__ float bfbits(unsigned u) {
  union { unsigned b; float f; } x; x.b = u; return x.f;
}

// Fused prep+cmat (runtime-proven R10-R13): writes C, dist, K(bf16), W.
__global__ __launch_bounds__(256)
void cmat2_kernel(const float* __restrict__ x, const float* __restrict__ y,
                  const float* __restrict__ species,
                  float* __restrict__ C, float* __restrict__ dist,
                  unsigned short* __restrict__ K, float* __restrict__ ws) {
  __shared__ float sp[P * 8];            // 16 KB: full species matrix
  const int tid = threadIdx.x;
  for (int q = tid; q < P * 8; q += 256) sp[q] = species[q];
  __syncthreads();

  const int g = blockIdx.x * 256 + tid;  // [0, TOT/4)
  const int base = g << 2;
  const int n = base >> 18;
  const int r = base & (PP - 1);
  const int i = r >> 9, j0 = r & (P - 1);
  const float* xp = x + ((n << 9) + i) * 3;
  const float x0 = xp[0], x1 = xp[1], x2 = xp[2];
  const float* yp = y + ((n << 9) + j0) * 3;
  const float* si = sp + i * 8;

  float c[4], d[4], wv[4];
  unsigned kk[4];
#pragma unroll
  for (int q = 0; q < 4; ++q) {
    const float* sj = sp + (j0 + q) * 8;
    float gd = 0.f;
#pragma unroll
    for (int k = 0; k < 8; ++k) gd = fmaf(si[k], sj[k], gd);
    const float w = fabsf(1.0f / gd + 1e-5f);
    wv[q] = w;
    float dx = x0 - yp[q * 3 + 0];
    float dy = x1 - yp[q * 3 + 1];
    float dz = x2 - yp[q * 3 + 2];
    dx = rintf(dx) - dx; dy = rintf(dy) - dy; dz = rintf(dz) - dz;
    const float ds = dx * dx + dy * dy + dz * dz;
    d[q] = ds;
    c[q] = ds * w;
    const float kf = __expf(-10.f * c[q]);
    const unsigned b = __float_as_uint(kf);
    kk[q] = (b + 0x7fffu + ((b >> 16) & 1u)) >> 16;   // RNE to bf16
  }

  f32x4 cv = { c[0], c[1], c[2], c[3] };
  f32x4 dv = { d[0], d[1], d[2], d[3] };
  *reinterpret_cast<f32x4*>(C + base)    = cv;
  *reinterpret_cast<f32x4*>(dist + base) = dv;
  uint2 kp;
  kp.x = kk[0] | (kk[1] << 16);
  kp.y = kk[2] | (kk[3] << 16);
  *reinterpret_cast<uint2*>(K + base) = kp;

  if (n == 0) {                                        // store W once for pi phase
    f32x4 wv4 = { wv[0], wv[1], wv[2], wv[3] };
    *reinterpret_cast<f32x4*>(ws + WS_W + base) = wv4;
  }
}

// ---- Fully-fused Sinkhorn + pi + cost. 128 blocks x 1024 threads, ONE block
// per batch: ALL cross-row/col exchange is __syncthreads. No atomics, no
// fences, no coop, no cross-block anything. Wave w owns rows w*32..w*32+31;
// lane owns 8 consecutive cols. Iteration is log-free: eu=mu/s, ev=mu/sc.
// pi = eu_i * ev_j * K_ij (since K = exp(-10C)); cost reduced block-locally.
__global__ __launch_bounds__(1024, 1)
void sink_f(const float* __restrict__ x, const float* __restrict__ y,
            const float* __restrict__ ws,
            float* __restrict__ pi, float* __restrict__ cost) {
  const unsigned short* Kus = (const unsigned short*)(ws + WS_K);
  const int tid  = threadIdx.x;
  const int lane = tid & 63;
  const int w    = tid >> 6;               // wave 0..15
  const int n    = blockIdx.x;             // batch

  __shared__ float ys[P * 3];              // 6 KB (pi phase)
  __shared__ float evLDS[P];               // 2 KB: exp(10*v_j)
  __shared__ float euLDS[P];               // 2 KB: exp(10*u_i) (last iter)
  __shared__ float cbuf[16][P];            // 32 KB: per-wave col partials

  {
    const float* yb = y + (size_t)(n << 9) * 3;
    for (int q = tid; q < P * 3; q += 1024) ys[q] = yb[q];
  }
  if (tid < P) evLDS[tid] = 1.0f;          // v = 0
  __syncthreads();

  const float muv = 1.0f / 512.0f + 1e-8f;
  // this wave's K base: row w*32 of batch n, this lane's 8 cols
  const unsigned short* Kw = Kus + (((size_t)(n << 9) + (w << 5)) << 9) + (lane << 3);

  for (int it = 0; it < MAX_IT; ++it) {
    f32x2 ev2[4], ca2[4];
#pragma unroll
    for (int t = 0; t < 4; ++t) {
      ev2[t] = *reinterpret_cast<const f32x2*>(&evLDS[(lane << 3) + (t << 1)]);
      ca2[t].x = 0.f; ca2[t].y = 0.f;
    }

#pragma unroll 2
    for (int rr = 0; rr < 32; rr += 4) {
      uint4 kw[4];
#pragma unroll
      for (int q = 0; q < 4; ++q)          // 4 loads in flight (latency cover)
        kw[q] = *reinterpret_cast<const uint4*>(Kw + ((rr + q) << 9));
#pragma unroll
      for (int q = 0; q < 4; ++q) {
        f32x2 k2[4];
        k2[0].x = bfbits(kw[q].x << 16); k2[0].y = bfbits(kw[q].x & 0xffff0000u);
        k2[1].x = bfbits(kw[q].y << 16); k2[1].y = bfbits(kw[q].y & 0xffff0000u);
        k2[2].x = bfbits(kw[q].z << 16); k2[2].y = bfbits(kw[q].z & 0xffff0000u);
        k2[3].x = bfbits(kw[q].w << 16); k2[3].y = bfbits(kw[q].w & 0xffff0000u);
        f32x2 s2 = {0.f, 0.f};
        s2 = pkfma(k2[0], ev2[0], s2);
        s2 = pkfma(k2[1], ev2[1], s2);
        s2 = pkfma(k2[2], ev2[2], s2);
        s2 = pkfma(k2[3], ev2[3], s2);
        float s = s2.x + s2.y;
#pragma unroll
        for (int o = 32; o > 0; o >>= 1) s += __shfl_xor(s, o);
        const float eu = __fdividef(muv, s);          // = exp(10*u_new)
        if (lane == 0) euLDS[(w << 5) + rr + q] = eu; // only last iter matters
        f32x2 eu2 = { eu, eu };
        ca2[0] = pkfma(k2[0], eu2, ca2[0]);
        ca2[1] = pkfma(k2[1], eu2, ca2[1]);
        ca2[2] = pkfma(k2[2], eu2, ca2[2]);
        ca2[3] = pkfma(k2[3], eu2, ca2[3]);
      }
    }
    {
      f32x4 s0 = { ca2[0].x, ca2[0].y, ca2[1].x, ca2[1].y };
      f32x4 s1 = { ca2[2].x, ca2[2].y, ca2[3].x, ca2[3].y };
      *reinterpret_cast<f32x4*>(&cbuf[w][lane << 3])       = s0;
      *reinterpret_cast<f32x4*>(&cbuf[w][(lane << 3) + 4]) = s1;
    }
    __syncthreads();
    if (tid < P) {
      float sc = 0.f;
#pragma unroll
      for (int q = 0; q < 16; ++q) sc += cbuf[q][tid];
      evLDS[tid] = __fdividef(muv, sc);    // = exp(10*v_new)
    }
    __syncthreads();
  }

  // ---- PI phase: pi = eu*ev*k ; cost = sum pi*C with C = ds*w recomputed.
  f32x2 ev2[4];
#pragma unroll
  for (int t = 0; t < 4; ++t)
    ev2[t] = *reinterpret_cast<const f32x2*>(&evLDS[(lane << 3) + (t << 1)]);

  const float* Wb = ws + WS_W;
  float costacc = 0.f;
  for (int r = 0; r < 32; ++r) {
    const int rl   = (w << 5) + r;         // local row
    const int rowg = (n << 9) + rl;
    const float* xp = x + (size_t)rowg * 3;
    const float x0 = xp[0], x1 = xp[1], x2 = xp[2];
    const float eu = euLDS[rl];
    uint4 kw = *reinterpret_cast<const uint4*>(Kw + (r << 9));
    float k[8];
    k[0] = bfbits(kw.x << 16); k[1] = bfbits(kw.x & 0xffff0000u);
    k[2] = bfbits(kw.y << 16); k[3] = bfbits(kw.y & 0xffff0000u);
    k[4] = bfbits(kw.z << 16); k[5] = bfbits(kw.z & 0xffff0000u);
    k[6] = bfbits(kw.w << 16); k[7] = bfbits(kw.w & 0xffff0000u);
    const float* Wr = Wb + (rl << 9) + (lane << 3);
    float4 w4a = *reinterpret_cast<const float4*>(Wr);
    float4 w4b = *reinterpret_cast<const float4*>(Wr + 4);
    float wv[8] = { w4a.x, w4a.y, w4a.z, w4a.w, w4b.x, w4b.y, w4b.z, w4b.w };
    float pq[8];
#pragma unroll
    for (int q = 0; q < 8; ++q) {
      const int j = (lane << 3) + q;
      float dx = x0 - ys[j * 3 + 0];
      float dy = x1 - ys[j * 3 + 1];
      float dz = x2 - ys[j * 3 + 2];
      dx = rintf(dx) - dx; dy = rintf(dy) - dy; dz = rintf(dz) - dz;
      const float Cq = (dx * dx + dy * dy + dz * dz) * wv[q];
      const float ev = ((const float*)&ev2[q >> 1])[q & 1];
      const float p  = eu * ev * k[q];
      pq[q] = p;
      costacc = fmaf(p, Cq, costacc);
    }
    float* Pr = pi + ((size_t)rowg << 9) + (lane << 3);
    f32x4 p0 = { pq[0], pq[1], pq[2], pq[3] };
    f32x4 p1 = { pq[4], pq[5], pq[6], pq[7] };
    *reinterpret_cast<f32x4*>(Pr)     = p0;
    *reinterpret_cast<f32x4*>(Pr + 4) = p1;
  }
#pragma unroll
  for (int o = 32; o > 0; o >>= 1) costacc += __shfl_xor(costacc, o);
  if (lane == 0) cbuf[0][w] = costacc;
  __syncthreads();
  if (tid == 0) {
    float cs = 0.f;
#pragma unroll
    for (int q = 0; q < 16; ++q) cs += cbuf[0][q];
    cost[n] = cs;                          // plain store, block owns batch
  }
}

extern "C" void kernel_launch(void* const* d_in, const int* in_sizes, int n_in,
                              void* d_out, int out_size, void* d_ws, size_t ws_size,
                              hipStream_t stream) {
  const float* x = (const float*)d_in[0];
  const float* y = (const float*)d_in[1];
  const float* species = (const float*)d_in[2];

  float* out  = (float*)d_out;
  float* cost = out;                     // 128
  float* pi   = out + 128;               // TOT
  float* C    = pi + (size_t)TOT;        // TOT
  float* dist = C + (size_t)TOT;         // TOT
  float* ws   = (float*)d_ws;

  hipLaunchKernelGGL(cmat2_kernel, dim3(TOT / 4 / 256), dim3(256), 0, stream,
                     x, y, species, C, dist, (unsigned short*)(ws + WS_K), ws);

  hipLaunchKernelGGL(sink_f, dim3(NB), dim3(1024), 0, stream,
                     x, y, ws, pi, cost);
}